// Round 3
// baseline (11.391 us; speedup 1.0000x reference)
//
#include <hip/hip_runtime.h>

// Closed-form 4-qubit circuit evaluation (see derivation in round 1):
//   out0 = cw0*c0       - sw0*s0*s1
//   out1 = cw1*c0c1     - sw1*s1*s2
//   out2 = cw2*c0c1c2   - sw2*s2*s3
//   out3 = cw3*c0c1c2c3 - sw3*s3
// with cq = cos x_q, sq = sin x_q (full angles), cwq/swq = cos/sin w_q.
//
// 4 batch elements per thread, stride blockDim between them so each load/store
// instruction is perfectly coalesced (lane i -> consecutive float4s).

#define ELEMS_PER_THREAD 4

__global__ __launch_bounds__(256) void quantum4_closed(
    const float* __restrict__ x, const float* __restrict__ w,
    float* __restrict__ out, int n)
{
    float cw0, sw0, cw1, sw1, cw2, sw2, cw3, sw3;
    __sincosf(w[0], &sw0, &cw0);
    __sincosf(w[1], &sw1, &cw1);
    __sincosf(w[2], &sw2, &cw2);
    __sincosf(w[3], &sw3, &cw3);

    const float4* __restrict__ xin = reinterpret_cast<const float4*>(x);
    float4* __restrict__ o4 = reinterpret_cast<float4*>(out);

    int base = blockIdx.x * (blockDim.x * ELEMS_PER_THREAD) + threadIdx.x;

    // Issue all loads first for MLP.
    float4 xv[ELEMS_PER_THREAD];
#pragma unroll
    for (int k = 0; k < ELEMS_PER_THREAD; ++k) {
        int idx = base + k * blockDim.x;
        if (idx < n) xv[k] = xin[idx];
    }

#pragma unroll
    for (int k = 0; k < ELEMS_PER_THREAD; ++k) {
        int idx = base + k * blockDim.x;
        if (idx >= n) continue;

        float s0, c0, s1, c1, s2, c2, s3, c3;
        __sincosf(xv[k].x, &s0, &c0);
        __sincosf(xv[k].y, &s1, &c1);
        __sincosf(xv[k].z, &s2, &c2);
        __sincosf(xv[k].w, &s3, &c3);

        float z1 = c0;
        float z2 = z1 * c1;
        float z3 = z2 * c2;
        float z4 = z3 * c3;

        float4 o;
        o.x = cw0 * z1 - sw0 * (s0 * s1);
        o.y = cw1 * z2 - sw1 * (s1 * s2);
        o.z = cw2 * z3 - sw2 * (s2 * s3);
        o.w = cw3 * z4 - sw3 * s3;

        o4[idx] = o;
    }
}

extern "C" void kernel_launch(void* const* d_in, const int* in_sizes, int n_in,
                              void* d_out, int out_size, void* d_ws, size_t ws_size,
                              hipStream_t stream) {
    const float* x = (const float*)d_in[0];   // [B,4] f32
    const float* w = (const float*)d_in[1];   // [4]   f32
    float* out = (float*)d_out;               // [B,4] f32

    int n = in_sizes[0] / 4;                  // B rows
    int block = 256;
    int per_block = block * ELEMS_PER_THREAD;
    int grid = (n + per_block - 1) / per_block;
    quantum4_closed<<<grid, block, 0, stream>>>(x, w, out, n);
}